// Round 1
// baseline (28291.104 us; speedup 1.0000x reference)
//
#include <hip/hip_runtime.h>
#include <hip/hip_bf16.h>

#define TSTEPS 2048
#define HD     1024
#define BATCH  8
#define NCLS   64
#define NBLK   128
#define UPB    8            // hidden units per block
#define RPB    32           // gate rows per block (8 units * 4 gates)
#define NWAVES 4
#define NFLAGS (NBLK * NWAVES)   // 512

// workspace byte offsets
#define OFF_WC    0            // bf16 [NBLK][RPB][HD]  = 8,388,608 B
#define OFF_BIAS  8388608      // f32 [4096]            = 16,384 B
#define OFF_HS    8404992      // f32 [TSTEPS+1][HD]    = 8,392,704 B
#define OFF_FLAGS 16797696     // u32 [NFLAGS]

__device__ __forceinline__ float blo(unsigned u) { return __uint_as_float(u << 16); }
__device__ __forceinline__ float bhi(unsigned u) { return __uint_as_float(u & 0xffff0000u); }
__device__ __forceinline__ float sigf(float x) { return 1.f / (1.f + __expf(-x)); }
__device__ __forceinline__ float tanhfast(float x) {
    float e = __expf(2.f * x);
    return 1.f - 2.f / (e + 1.f);
}

__device__ __forceinline__ void st_rlx_f32(float* p, float v) {
    __hip_atomic_store(p, v, __ATOMIC_RELAXED, __HIP_MEMORY_SCOPE_AGENT);
}
__device__ __forceinline__ void st_rel_u32(unsigned* p, unsigned v) {
    __hip_atomic_store(p, v, __ATOMIC_RELEASE, __HIP_MEMORY_SCOPE_AGENT);
}
__device__ __forceinline__ void st_rlx_u32(unsigned* p, unsigned v) {
    __hip_atomic_store(p, v, __ATOMIC_RELAXED, __HIP_MEMORY_SCOPE_AGENT);
}
__device__ __forceinline__ unsigned long long ld_rlx_u64(const unsigned long long* p) {
    return __hip_atomic_load((unsigned long long*)p, __ATOMIC_RELAXED, __HIP_MEMORY_SCOPE_AGENT);
}
__device__ __forceinline__ bool chk2(unsigned long long v, unsigned t) {
    return ((unsigned)v >= t) && ((unsigned)(v >> 32) >= t);
}
__device__ __forceinline__ float dot8(uint4 wv, const float* h) {
    float a = 0.f;
    a = fmaf(blo(wv.x), h[0], a); a = fmaf(bhi(wv.x), h[1], a);
    a = fmaf(blo(wv.y), h[2], a); a = fmaf(bhi(wv.y), h[3], a);
    a = fmaf(blo(wv.z), h[4], a); a = fmaf(bhi(wv.z), h[5], a);
    a = fmaf(blo(wv.w), h[6], a); a = fmaf(bhi(wv.w), h[7], a);
    return a;
}

// ---- prep 1: bias sum, zero hs[0], zero flags ----
__global__ void prep_misc(const float* __restrict__ bih, const float* __restrict__ bhh,
                          float* __restrict__ bias, float* hs, unsigned* flags) {
    int idx = blockIdx.x * 256 + threadIdx.x;
    if (idx < 4096) bias[idx] = bih[idx] + bhh[idx];
    if (idx < HD)   st_rlx_f32(&hs[idx], 0.f);
    if (idx < NFLAGS) st_rlx_u32(&flags[idx], 0u);
}

// ---- prep 2: Wc = bf16(W_ih + W_hh), reordered into per-block LDS layout ----
// layout: wc[blk][rr][k], rr = unit_local*4 + gate, global row = gate*1024 + blk*8 + unit_local
__global__ void prep_wc(const float* __restrict__ wih, const float* __restrict__ whh,
                        unsigned short* __restrict__ wc) {
    int idx = blockIdx.x * 256 + threadIdx.x;   // 0 .. 128*32*1024
    int blk = idx >> 15;
    int rem = idx & 32767;
    int rr  = rem >> 10;
    int k   = rem & 1023;
    int grow = (rr & 3) * 1024 + blk * UPB + (rr >> 2);
    float v = wih[grow * 1024 + k] + whh[grow * 1024 + k];
    unsigned u = __float_as_uint(v);
    unsigned r = (u + 0x7fffu + ((u >> 16) & 1u)) >> 16;   // RNE to bf16
    wc[idx] = (unsigned short)r;
}

// ---- persistent LSTM kernel: 128 blocks x 256 threads ----
__global__ __launch_bounds__(256) void lstm_kernel(const unsigned short* __restrict__ wc,
                                                   const float* __restrict__ bias,
                                                   float* hs, unsigned* flags) {
    __shared__ unsigned short wlds[RPB * HD];   // 64 KiB

    const int tid = threadIdx.x;
    const int w   = tid >> 6;
    const int l   = tid & 63;
    const int blk = blockIdx.x;

    // stage W slice (contiguous 64 KiB) into LDS
    {
        const uint4* src = (const uint4*)(wc + (size_t)blk * RPB * HD);
        uint4* dst = (uint4*)wlds;
        #pragma unroll
        for (int i = 0; i < 16; ++i) dst[tid + i * 256] = src[tid + i * 256];
    }
    // biases for this wave's 8 rows (units 2w,2w+1 x gates i,f,g,o)
    float brow[8];
    #pragma unroll
    for (int k2 = 0; k2 < 8; ++k2) {
        int rr = 8 * w + k2;
        brow[k2] = bias[(rr & 3) * 1024 + blk * UPB + (rr >> 2)];
    }
    __syncthreads();

    const int wid   = blk * NWAVES + w;
    const int ubase = blk * UPB + 2 * w;
    float c0 = 0.f, c1 = 0.f;
    const unsigned long long* flg64 = (const unsigned long long*)flags;

    for (int t = 0; t < TSTEPS; ++t) {
        if (t > 0) {
            const unsigned tt = (unsigned)t;
            for (;;) {
                unsigned long long f0 = ld_rlx_u64(flg64 + 4 * l + 0);
                unsigned long long f1 = ld_rlx_u64(flg64 + 4 * l + 1);
                unsigned long long f2 = ld_rlx_u64(flg64 + 4 * l + 2);
                unsigned long long f3 = ld_rlx_u64(flg64 + 4 * l + 3);
                bool ok = chk2(f0, tt) && chk2(f1, tt) && chk2(f2, tt) && chk2(f3, tt);
                if (__all(ok)) break;
            }
        }
        // load h_{t-1}: lane l covers elems [8l,8l+8) and [512+8l, 512+8l+8)
        float hA[8], hB[8];
        {
            const unsigned long long* hsrc = (const unsigned long long*)(hs + (size_t)t * HD);
            #pragma unroll
            for (int j = 0; j < 4; ++j) {
                unsigned long long v = ld_rlx_u64(hsrc + 4 * l + j);
                hA[2 * j]     = __uint_as_float((unsigned)v);
                hA[2 * j + 1] = __uint_as_float((unsigned)(v >> 32));
            }
            #pragma unroll
            for (int j = 0; j < 4; ++j) {
                unsigned long long v = ld_rlx_u64(hsrc + 256 + 4 * l + j);
                hB[2 * j]     = __uint_as_float((unsigned)v);
                hB[2 * j + 1] = __uint_as_float((unsigned)(v >> 32));
            }
        }
        // 8 gate-row dot products
        float accs[8];
        #pragma unroll
        for (int k2 = 0; k2 < 8; ++k2) {
            int rr = 8 * w + k2;
            const uint4* wrow = (const uint4*)(wlds + rr * HD);
            uint4 wa = wrow[l];
            uint4 wb = wrow[64 + l];
            accs[k2] = dot8(wa, hA) + dot8(wb, hB);
        }
        // wave butterfly reduce + bias
        #pragma unroll
        for (int k2 = 0; k2 < 8; ++k2) {
            float a = accs[k2];
            a += __shfl_xor(a, 32); a += __shfl_xor(a, 16); a += __shfl_xor(a, 8);
            a += __shfl_xor(a, 4);  a += __shfl_xor(a, 2);  a += __shfl_xor(a, 1);
            accs[k2] = a + brow[k2];
        }
        // cell update (replicated across lanes), gates order i,f,g,o
        float i0 = sigf(accs[0]), f0 = sigf(accs[1]), g0 = tanhfast(accs[2]), o0 = sigf(accs[3]);
        c0 = f0 * c0 + i0 * g0;
        float h0 = o0 * tanhfast(c0);
        float i1 = sigf(accs[4]), f1 = sigf(accs[5]), g1 = tanhfast(accs[6]), o1 = sigf(accs[7]);
        c1 = f1 * c1 + i1 * g1;
        float h1 = o1 * tanhfast(c1);

        if (l < 2) st_rlx_f32(hs + (size_t)(t + 1) * HD + ubase + l, (l == 0) ? h0 : h1);
        // release: waits the wave's outstanding stores, then publishes
        if (l == 0) st_rel_u32(flags + wid, (unsigned)(t + 1));
    }
}

// ---- epilogue: neck[b][c][t] = (x[b][c][t] + hs[t+1][c]) * mask[b][t] ----
__global__ void neck_kernel(const float* __restrict__ x, const float* __restrict__ masks,
                            const float* __restrict__ hs, float* __restrict__ out) {
    int t0 = blockIdx.x * 64, c0 = blockIdx.y * 32;
    __shared__ float tile[32][65];
    int tid = threadIdx.x;
    for (int i = tid; i < 64 * 32; i += 256) {
        int tl = i >> 5, cl = i & 31;
        tile[cl][tl] = hs[(size_t)(t0 + tl + 1) * HD + c0 + cl];
    }
    __syncthreads();
    int tl = tid & 63, cb = tid >> 6;
    for (int b = 0; b < BATCH; ++b) {
        float m = masks[b * TSTEPS + t0 + tl];
        #pragma unroll
        for (int cc = cb; cc < 32; cc += 4) {
            size_t idx = ((size_t)b * 1024 + (c0 + cc)) * TSTEPS + t0 + tl;
            out[idx] = (x[idx] + tile[cc][tl]) * m;
        }
    }
}

// ---- epilogue: frames[b][t][n] = (hs[t+1] . W_fc[n] + b_fc[n]) * mask[b][t] ----
__global__ void frames_kernel(const float* __restrict__ hs, const float* __restrict__ wfc,
                              const float* __restrict__ bfc, const float* __restrict__ masks,
                              float* __restrict__ out2) {
    int t = blockIdx.x;
    __shared__ float hrow[HD];
    int tid = threadIdx.x;
    for (int i = tid; i < HD; i += 256) hrow[i] = hs[(size_t)(t + 1) * HD + i];
    __syncthreads();
    int n = tid >> 2, p = tid & 3;
    const float* wr = wfc + n * HD + p * 256;
    const float* hr = hrow + p * 256;
    float acc = 0.f;
    #pragma unroll 8
    for (int j = 0; j < 256; ++j) acc = fmaf(wr[j], hr[j], acc);
    acc += __shfl_xor(acc, 1);
    acc += __shfl_xor(acc, 2);
    float v = acc + bfc[n];
    if (p == 0) {
        for (int b = 0; b < BATCH; ++b) {
            float m = masks[b * TSTEPS + t];
            out2[((size_t)b * TSTEPS + t) * NCLS + n] = v * m;
        }
    }
}

extern "C" void kernel_launch(void* const* d_in, const int* in_sizes, int n_in,
                              void* d_out, int out_size, void* d_ws, size_t ws_size,
                              hipStream_t stream) {
    const float* x     = (const float*)d_in[0];
    const float* masks = (const float*)d_in[1];
    const float* wih   = (const float*)d_in[2];
    const float* whh   = (const float*)d_in[3];
    const float* bih   = (const float*)d_in[4];
    const float* bhh   = (const float*)d_in[5];
    const float* wfc   = (const float*)d_in[6];
    const float* bfc   = (const float*)d_in[7];
    float* out = (float*)d_out;

    char* ws = (char*)d_ws;
    unsigned short* wc = (unsigned short*)(ws + OFF_WC);
    float* bias        = (float*)(ws + OFF_BIAS);
    float* hs          = (float*)(ws + OFF_HS);
    unsigned* flags    = (unsigned*)(ws + OFF_FLAGS);

    hipLaunchKernelGGL(prep_misc, dim3(16), dim3(256), 0, stream, bih, bhh, bias, hs, flags);
    hipLaunchKernelGGL(prep_wc, dim3(16384), dim3(256), 0, stream, wih, whh, wc);
    hipLaunchKernelGGL(lstm_kernel, dim3(NBLK), dim3(256), 0, stream, wc, bias, hs, flags);
    hipLaunchKernelGGL(neck_kernel, dim3(32, 32), dim3(256), 0, stream, x, masks, hs, out);
    hipLaunchKernelGGL(frames_kernel, dim3(2048), dim3(256), 0, stream, hs, wfc, bfc, masks,
                       out + (size_t)BATCH * 1024 * TSTEPS);
}

// Round 2
// 9597.613 us; speedup vs baseline: 2.9477x; 2.9477x over previous
//
#include <hip/hip_runtime.h>
#include <hip/hip_bf16.h>

#define TSTEPS 2048
#define HD     1024
#define BATCH  8
#define NCLS   64
#define NBLK   128
#define UPB    8            // hidden units per block
#define RPB    32           // gate rows per block (8 units * 4 gates)
#define NWAVES 4

// workspace byte offsets
#define OFF_WC    0            // bf16 [NBLK][RPB][HD]  = 8,388,608 B
#define OFF_BIAS  8388608      // f32 [4096]            = 16,384 B
#define OFF_HS2   8404992      // u32 [TSTEPS+1][HD]    = 8,392,704 B (bf16 val | 16-bit tag)

__device__ __forceinline__ float blo(unsigned u) { return __uint_as_float(u << 16); }
__device__ __forceinline__ float bhi(unsigned u) { return __uint_as_float(u & 0xffff0000u); }
__device__ __forceinline__ float sigf(float x) { return 1.f / (1.f + __expf(-x)); }
__device__ __forceinline__ float tanhfast(float x) {
    float e = __expf(2.f * x);
    return 1.f - 2.f / (e + 1.f);
}
__device__ __forceinline__ unsigned f32_to_bf16_rne(float f) {
    unsigned u = __float_as_uint(f);
    return (u + 0x7fffu + ((u >> 16) & 1u)) >> 16;
}

__device__ __forceinline__ void st_rlx_u32(unsigned* p, unsigned v) {
    __hip_atomic_store(p, v, __ATOMIC_RELAXED, __HIP_MEMORY_SCOPE_AGENT);
}
__device__ __forceinline__ void st_rlx_u64(unsigned long long* p, unsigned long long v) {
    __hip_atomic_store(p, v, __ATOMIC_RELAXED, __HIP_MEMORY_SCOPE_AGENT);
}
__device__ __forceinline__ unsigned long long ld_rlx_u64(const unsigned long long* p) {
    return __hip_atomic_load((unsigned long long*)p, __ATOMIC_RELAXED, __HIP_MEMORY_SCOPE_AGENT);
}
__device__ __forceinline__ float dot8(uint4 wv, const float* h) {
    float a = 0.f;
    a = fmaf(blo(wv.x), h[0], a); a = fmaf(bhi(wv.x), h[1], a);
    a = fmaf(blo(wv.y), h[2], a); a = fmaf(bhi(wv.y), h[3], a);
    a = fmaf(blo(wv.z), h[4], a); a = fmaf(bhi(wv.z), h[5], a);
    a = fmaf(blo(wv.w), h[6], a); a = fmaf(bhi(wv.w), h[7], a);
    return a;
}

// ---- prep 1: bias sum, init hs2 row 0 (val=0, tag=0) ----
__global__ void prep_misc(const float* __restrict__ bih, const float* __restrict__ bhh,
                          float* __restrict__ bias, unsigned* hs2) {
    int idx = blockIdx.x * 256 + threadIdx.x;
    if (idx < 4096) bias[idx] = bih[idx] + bhh[idx];
    if (idx < HD)   hs2[idx] = 0u;   // bf16(0)<<16 | tag 0
}

// ---- prep 2: Wc = bf16(W_ih + W_hh), reordered into per-block LDS layout ----
__global__ void prep_wc(const float* __restrict__ wih, const float* __restrict__ whh,
                        unsigned short* __restrict__ wc) {
    int idx = blockIdx.x * 256 + threadIdx.x;
    int blk = idx >> 15;
    int rem = idx & 32767;
    int rr  = rem >> 10;
    int k   = rem & 1023;
    int grow = (rr & 3) * 1024 + blk * UPB + (rr >> 2);
    float v = wih[grow * 1024 + k] + whh[grow * 1024 + k];
    wc[idx] = (unsigned short)f32_to_bf16_rne(v);
}

// ---- persistent LSTM kernel: 128 blocks x 256 threads ----
__global__ __launch_bounds__(256) void lstm_kernel(const unsigned short* __restrict__ wc,
                                                   const float* __restrict__ bias,
                                                   unsigned* hs2) {
    __shared__ unsigned short wlds[RPB * HD];   // 64 KiB
    __shared__ unsigned hbuf[HD];               // 4 KiB raw packed row

    const int tid = threadIdx.x;
    const int w   = tid >> 6;
    const int l   = tid & 63;
    const int blk = blockIdx.x;

    // stage W slice (contiguous 64 KiB) into LDS
    {
        const uint4* src = (const uint4*)(wc + (size_t)blk * RPB * HD);
        uint4* dst = (uint4*)wlds;
        #pragma unroll
        for (int i = 0; i < 16; ++i) dst[tid + i * 256] = src[tid + i * 256];
    }
    // biases for this wave's 8 rows (units 2w,2w+1 x gates i,f,g,o)
    float brow[8];
    #pragma unroll
    for (int k2 = 0; k2 < 8; ++k2) {
        int rr = 8 * w + k2;
        brow[k2] = bias[(rr & 3) * 1024 + blk * UPB + (rr >> 2)];
    }
    __syncthreads();

    const int ubase = blk * UPB + 2 * w;
    float c0 = 0.f, c1 = 0.f;

    for (int t = 0; t < TSTEPS; ++t) {
        if (w == 0) {
            // wave 0: poll row t until every (val|tag) word carries tag==t
            const unsigned long long* r64 = (const unsigned long long*)(hs2 + (size_t)t * HD);
            const unsigned tt = (unsigned)t;
            unsigned long long A[4], Bv[4];
            for (;;) {
                #pragma unroll
                for (int j = 0; j < 4; ++j) A[j] = ld_rlx_u64(r64 + 4 * l + j);
                #pragma unroll
                for (int j = 0; j < 4; ++j) Bv[j] = ld_rlx_u64(r64 + 256 + 4 * l + j);
                bool ok = true;
                #pragma unroll
                for (int j = 0; j < 4; ++j) {
                    ok = ok && ((unsigned)A[j]  & 0xffffu) == tt && ((unsigned)(A[j]  >> 32) & 0xffffu) == tt;
                    ok = ok && ((unsigned)Bv[j] & 0xffffu) == tt && ((unsigned)(Bv[j] >> 32) & 0xffffu) == tt;
                }
                if (__all(ok)) break;
            }
            // deposit raw packed row into LDS
            unsigned long long* hb64 = (unsigned long long*)hbuf;
            #pragma unroll
            for (int j = 0; j < 4; ++j) hb64[4 * l + j] = A[j];
            #pragma unroll
            for (int j = 0; j < 4; ++j) hb64[256 + 4 * l + j] = Bv[j];
        }
        __syncthreads();

        // all waves: read h_{t-1} from LDS, unpack bf16 (value sits in high 16 bits)
        float hA[8], hB[8];
        {
            const uint4* hb = (const uint4*)hbuf;
            uint4 a0 = hb[2 * l], a1 = hb[2 * l + 1];
            uint4 b0 = hb[128 + 2 * l], b1 = hb[128 + 2 * l + 1];
            hA[0] = bhi(a0.x); hA[1] = bhi(a0.y); hA[2] = bhi(a0.z); hA[3] = bhi(a0.w);
            hA[4] = bhi(a1.x); hA[5] = bhi(a1.y); hA[6] = bhi(a1.z); hA[7] = bhi(a1.w);
            hB[0] = bhi(b0.x); hB[1] = bhi(b0.y); hB[2] = bhi(b0.z); hB[3] = bhi(b0.w);
            hB[4] = bhi(b1.x); hB[5] = bhi(b1.y); hB[6] = bhi(b1.z); hB[7] = bhi(b1.w);
        }
        // 8 gate-row dot products
        float accs[8];
        #pragma unroll
        for (int k2 = 0; k2 < 8; ++k2) {
            int rr = 8 * w + k2;
            const uint4* wrow = (const uint4*)(wlds + rr * HD);
            uint4 wa = wrow[l];
            uint4 wb = wrow[64 + l];
            accs[k2] = dot8(wa, hA) + dot8(wb, hB);
        }
        // wave butterfly reduce + bias
        #pragma unroll
        for (int k2 = 0; k2 < 8; ++k2) {
            float a = accs[k2];
            a += __shfl_xor(a, 32); a += __shfl_xor(a, 16); a += __shfl_xor(a, 8);
            a += __shfl_xor(a, 4);  a += __shfl_xor(a, 2);  a += __shfl_xor(a, 1);
            accs[k2] = a + brow[k2];
        }
        // cell update (replicated across lanes), gate order i,f,g,o
        float ii0 = sigf(accs[0]), ff0 = sigf(accs[1]), gg0 = tanhfast(accs[2]), oo0 = sigf(accs[3]);
        c0 = ff0 * c0 + ii0 * gg0;
        float h0 = oo0 * tanhfast(c0);
        float ii1 = sigf(accs[4]), ff1 = sigf(accs[5]), gg1 = tanhfast(accs[6]), oo1 = sigf(accs[7]);
        c1 = ff1 * c1 + ii1 * gg1;
        float h1 = oo1 * tanhfast(c1);

        // publish both units as one u64: (bf16|tag) x2. Data-carried tag: no fence needed.
        if (l == 0) {
            unsigned tag = (unsigned)(t + 1);
            unsigned p0 = (f32_to_bf16_rne(h0) << 16) | tag;
            unsigned p1 = (f32_to_bf16_rne(h1) << 16) | tag;
            st_rlx_u64((unsigned long long*)(hs2 + (size_t)(t + 1) * HD + ubase),
                       ((unsigned long long)p1 << 32) | p0);
        }
    }
}

// ---- epilogue: neck[b][c][t] = (x[b][c][t] + h[t][c]) * mask[b][t] ----
__global__ void neck_kernel(const float* __restrict__ x, const float* __restrict__ masks,
                            const unsigned* __restrict__ hs2, float* __restrict__ out) {
    int t0 = blockIdx.x * 64, c0 = blockIdx.y * 32;
    __shared__ float tile[32][65];
    int tid = threadIdx.x;
    for (int i = tid; i < 64 * 32; i += 256) {
        int tl = i >> 5, cl = i & 31;
        tile[cl][tl] = bhi(hs2[(size_t)(t0 + tl + 1) * HD + c0 + cl]);
    }
    __syncthreads();
    int tl = tid & 63, cb = tid >> 6;
    for (int b = 0; b < BATCH; ++b) {
        float m = masks[b * TSTEPS + t0 + tl];
        #pragma unroll
        for (int cc = cb; cc < 32; cc += 4) {
            size_t idx = ((size_t)b * 1024 + (c0 + cc)) * TSTEPS + t0 + tl;
            out[idx] = (x[idx] + tile[cc][tl]) * m;
        }
    }
}

// ---- epilogue: frames[b][t][n] = (h[t] . W_fc[n] + b_fc[n]) * mask[b][t] ----
__global__ void frames_kernel(const unsigned* __restrict__ hs2, const float* __restrict__ wfc,
                              const float* __restrict__ bfc, const float* __restrict__ masks,
                              float* __restrict__ out2) {
    int t = blockIdx.x;
    __shared__ float hrow[HD];
    int tid = threadIdx.x;
    for (int i = tid; i < HD; i += 256) hrow[i] = bhi(hs2[(size_t)(t + 1) * HD + i]);
    __syncthreads();
    int n = tid >> 2, p = tid & 3;
    const float* wr = wfc + n * HD + p * 256;
    const float* hr = hrow + p * 256;
    float acc = 0.f;
    #pragma unroll 8
    for (int j = 0; j < 256; ++j) acc = fmaf(wr[j], hr[j], acc);
    acc += __shfl_xor(acc, 1);
    acc += __shfl_xor(acc, 2);
    float v = acc + bfc[n];
    if (p == 0) {
        for (int b = 0; b < BATCH; ++b) {
            float m = masks[b * TSTEPS + t];
            out2[((size_t)b * TSTEPS + t) * NCLS + n] = v * m;
        }
    }
}

extern "C" void kernel_launch(void* const* d_in, const int* in_sizes, int n_in,
                              void* d_out, int out_size, void* d_ws, size_t ws_size,
                              hipStream_t stream) {
    const float* x     = (const float*)d_in[0];
    const float* masks = (const float*)d_in[1];
    const float* wih   = (const float*)d_in[2];
    const float* whh   = (const float*)d_in[3];
    const float* bih   = (const float*)d_in[4];
    const float* bhh   = (const float*)d_in[5];
    const float* wfc   = (const float*)d_in[6];
    const float* bfc   = (const float*)d_in[7];
    float* out = (float*)d_out;

    char* ws = (char*)d_ws;
    unsigned short* wc = (unsigned short*)(ws + OFF_WC);
    float* bias        = (float*)(ws + OFF_BIAS);
    unsigned* hs2      = (unsigned*)(ws + OFF_HS2);

    hipLaunchKernelGGL(prep_misc, dim3(16), dim3(256), 0, stream, bih, bhh, bias, hs2);
    hipLaunchKernelGGL(prep_wc, dim3(16384), dim3(256), 0, stream, wih, whh, wc);
    hipLaunchKernelGGL(lstm_kernel, dim3(NBLK), dim3(256), 0, stream, wc, bias, hs2);
    hipLaunchKernelGGL(neck_kernel, dim3(32, 32), dim3(256), 0, stream, x, masks, hs2, out);
    hipLaunchKernelGGL(frames_kernel, dim3(2048), dim3(256), 0, stream, hs2, wfc, bfc, masks,
                       out + (size_t)BATCH * 1024 * TSTEPS);
}